// Round 26
// baseline (55.571 us; speedup 1.0000x reference)
//
#include <hip/hip_runtime.h>
#include <hip/hip_bf16.h>

// Problem constants
#define B_ROWS 4096
#define NN     8192
#define DD     128
#define NSPLIT 64           // split s of row n = the "other" tile index
#define NTRI   2080         // 64*65/2 upper-triangular tiles
#define NBLK   768          // persistent blocks: exactly 3 per CU (53.2 KB LDS)
#define SPA    68           // s2m panel row stride in u16 (136 B, 8B-aligned stores)
#define CSHIFT 128.0f       // fixed logsumexp shift (log2 domain)

typedef __attribute__((ext_vector_type(8))) short s8v;   // 8 bf16 (4 VGPR)
typedef __attribute__((ext_vector_type(4))) float f4v;   // 4 f32
typedef __attribute__((ext_vector_type(2))) float f2v;
typedef __attribute__((ext_vector_type(4))) unsigned short u16x4;
typedef unsigned int u32;

static constexpr float SCALE_H = 1.6986436f;      // sqrt(2*log2(e)); folds /TEMP and log2e into the matmul
static constexpr float SCALE2  = 2.8853900818f;   // 2*log2(e)
static constexpr float LN2     = 0.6931471805599453f;

__device__ __forceinline__ float fast_exp2(float x) {
#if __has_builtin(__builtin_amdgcn_exp2f)
    return __builtin_amdgcn_exp2f(x);      // bare v_exp_f32
#else
    return exp2f(x);
#endif
}

// (1 - x^2) with mask folded in, rounded to bf16 bits
__device__ __forceinline__ unsigned short s2m_pack(float x, bool msk) {
    float s2 = msk ? 0.f : 1.f - x * x;    // s2m=0 => exp2(-CSHIFT) -> ~0
    union { __hip_bfloat16 h; unsigned short u; } cv;
    cv.h = __float2bfloat16(s2);
    return cv.u;
}

__device__ __forceinline__ float bf16f(unsigned short u) {
    return __uint_as_float(((u32)u) << 16);
}

typedef __attribute__((address_space(1))) const u32 gu32;
typedef __attribute__((address_space(3))) u32 lu32;
__device__ __forceinline__ void gload_lds16(const void* g, void* l) {
    // async global->LDS, 16B/lane; dest = lds base + lane*16 (wave-uniform base)
    __builtin_amdgcn_global_load_lds((gu32*)g, (lu32*)l, 16, 0, 0);
}

// triangular decode: bid -> (i,j), i <= j  (exact after integer fixup)
__device__ __forceinline__ void tri_decode(int b, int& io, int& jo) {
    int j = (int)((sqrtf(8.f * (float)b + 1.f) - 1.f) * 0.5f);
    while (((j + 1) * (j + 2)) / 2 <= b) ++j;
    while ((j * (j + 1)) / 2 > b) --j;
    jo = j; io = b - (j * (j + 1)) / 2;
}

// ---- kernel 1: fused bf16-prep + pos dot ----
__global__ void hpos_kernel(const float* __restrict__ hi, const float* __restrict__ hj,
                            __hip_bfloat16* __restrict__ hb, float* __restrict__ pos2) {
    int w = threadIdx.x >> 6, l = threadIdx.x & 63;
    int row = blockIdx.x * 4 + w;
    f2v a = ((const f2v*)(hi + (size_t)row * DD))[l];
    f2v b = ((const f2v*)(hj + (size_t)row * DD))[l];
    float d = a[0] * b[0] + a[1] * b[1];
    #pragma unroll
    for (int off = 32; off; off >>= 1) d += __shfl_xor(d, off, 64);
    if (l == 0) pos2[row] = SCALE2 * d;
    union { ushort2 u2; __hip_bfloat16 h[2]; } ua, ub;
    ua.h[0] = __float2bfloat16(a[0] * SCALE_H);
    ua.h[1] = __float2bfloat16(a[1] * SCALE_H);
    ub.h[0] = __float2bfloat16(b[0] * SCALE_H);
    ub.h[1] = __float2bfloat16(b[1] * SCALE_H);
    ((ushort2*)(hb + (size_t)row * DD))[l] = ua.u2;
    ((ushort2*)(hb + (size_t)(row + B_ROWS) * DD))[l] = ub.u2;
}

// ---- kernel 2: persistent symmetric-tile sweep ----
// 768 blocks (exactly 3/CU co-resident), each loops over 2-3 consecutive
// triangular tiles with the R24 per-tile body (longest-latency-first
// prologue, 2 barriers/tile). Block-level TLP (24 waves/CU) hides each
// tile's prologue latency; no dispatch ramp; tail = 1 tile.
__global__ __launch_bounds__(512, 4)
void main_kernel(const __hip_bfloat16* __restrict__ hb, const float* __restrict__ S,
                 float* __restrict__ ssplit) {
    __shared__ short ldsB[128][128];           // 32 KB B tile (row-swizzled)
    __shared__ unsigned short sA[64][SPA];     // 8.5 KB row-view s2m (bf16)
    __shared__ unsigned short sB[64][SPA];     // 8.5 KB col-view s2m (bf16)
    __shared__ float mrg[768];                 // 3 KB merge scratch

    // XCD-contiguous block remap (768 = 8 x 96) + tile range [start, end)
    const int orig = blockIdx.x;
    const int rb   = (orig & 7) * (NBLK / 8) + (orig >> 3);
    const int start = (rb * NTRI) / NBLK;
    const int end   = ((rb + 1) * NTRI) / NBLK;   // 2 or 3 tiles

    const int tid = threadIdx.x;
    const int l  = tid & 63;
    const int w  = tid >> 6;                   // 0..7
    const int wm = w >> 1, wn = w & 1;
    const int lc = l & 15;                     // frag row/col within 16
    const int lk = l >> 4;                     // k-group
    const int prr = tid >> 3;                  // 0..63 (panel row)
    const int pc8 = (tid & 7) * 8;             // 0..56 (panel col base)

    const s8v* hb8 = (const s8v*)hb;           // 16 x s8v per row of 128 bf16

    for (int t = start; t < end; ++t) {
        int i, j;
        tri_decode(t, i, j);
        const bool diag = (i == j);
        const int r64 = i * 64, c64 = j * 64;

        // ---- (1) col-view S gather FIRST: longest memory chain
        f4v b0, b1;
        {
            const float* gB = S + (size_t)(c64 + prr) * B_ROWS + r64 + pc8;
            b0 = ((const f4v*)gB)[0]; b1 = ((const f4v*)gB)[1];
        }

        // ---- (2) async B tile stage: 128 hb-rows; 4 gloads/wave
        #pragma unroll
        for (int i2 = 0; i2 < 4; i2++) {
            const int rowb = w * 16 + i2 * 4;
            const int lrw  = rowb + lk;        // local row 0..127
            const int grow = c64 + ((lrw < 64) ? lrw : (lrw - 64 + B_ROWS));
            const int sc16 = lc ^ (lrw & 7);   // source pre-swizzle
            gload_lds16((const char*)hb + ((size_t)grow << 8) + (sc16 << 4),
                        (char*)&ldsB[rowb][0]);
        }

        // ---- (3) row-view S loads (coalesced)
        f4v a0, a1;
        {
            const float* gA = S + (size_t)(r64 + prr) * B_ROWS + c64 + pc8;
            a0 = ((const f4v*)gA)[0]; a1 = ((const f4v*)gA)[1];
        }

        // ---- (4) A fragments: wave's 16 pair-rows x 2 halves
        s8v afr[2][4];
        #pragma unroll
        for (int fm = 0; fm < 2; fm++) {
            int ar = (r64 + wm * 16 + lc) + fm * B_ROWS;
            #pragma unroll
            for (int kk = 0; kk < 4; kk++)
                afr[fm][kk] = hb8[ar * 16 + kk * 4 + lk];
        }

        // ---- (5) pack s2m panels (consumes a/b as they land)
        {
            u16x4 pa0, pa1, pb0, pb1;
            #pragma unroll
            for (int e = 0; e < 4; e++) {
                pa0[e] = s2m_pack(a0[e], diag && (pc8 + e     == prr));
                pa1[e] = s2m_pack(a1[e], diag && (pc8 + 4 + e == prr));
                pb0[e] = s2m_pack(b0[e], false);   // col-view discarded on diag
                pb1[e] = s2m_pack(b1[e], false);
            }
            *(u16x4*)&sA[prr][pc8]     = pa0;
            *(u16x4*)&sA[prr][pc8 + 4] = pa1;
            *(u16x4*)&sB[prr][pc8]     = pb0;
            *(u16x4*)&sB[prr][pc8 + 4] = pb1;
        }
        __syncthreads();   // barrier1: B tile + panels + afr ready

        // ---- MFMA: 32 per wave (fm2 x fh2 x cg2 x kk4), acc[fm][fh][cg]
        const char* bp[4];
        {
            const char* bb = (const char*)ldsB + (wn * 32 + lc) * 256;
            #pragma unroll
            for (int kk = 0; kk < 4; kk++)
                bp[kk] = bb + (((kk * 4 + lk) ^ (lc & 7)) << 4);
        }
        f4v acc[2][2][2];
        #pragma unroll
        for (int fm = 0; fm < 2; fm++)
            #pragma unroll
            for (int fh = 0; fh < 2; fh++)
                #pragma unroll
                for (int cg = 0; cg < 2; cg++) acc[fm][fh][cg] = f4v{0.f, 0.f, 0.f, 0.f};
        #pragma unroll
        for (int kk = 0; kk < 4; kk++) {
            #pragma unroll
            for (int fh = 0; fh < 2; fh++)
                #pragma unroll
                for (int cg = 0; cg < 2; cg++) {
                    s8v bf = *(const s8v*)(bp[kk] + fh * 16384 + cg * 4096);
                    acc[0][fh][cg] = __builtin_amdgcn_mfma_f32_16x16x32_bf16(
                        afr[0][kk], bf, acc[0][fh][cg], 0, 0, 0);
                    acc[1][fh][cg] = __builtin_amdgcn_mfma_f32_16x16x32_bf16(
                        afr[1][kk], bf, acc[1][fh][cg], 0, 0, 0);
                }
        }

        // ---- dual epilogue: row-view (sA[rr][cc]) + col-view (sB[cc][rr])
        float rsum[2][4], csum[2][2];
        #pragma unroll
        for (int fm = 0; fm < 2; fm++)
            #pragma unroll
            for (int r = 0; r < 4; r++) rsum[fm][r] = 0.f;
        csum[0][0] = csum[0][1] = csum[1][0] = csum[1][1] = 0.f;

        #pragma unroll
        for (int r = 0; r < 4; r++) {
            const int rr = wm * 16 + lk * 4 + r;
            #pragma unroll
            for (int cg = 0; cg < 2; cg++) {
                const int cc = wn * 32 + cg * 16 + lc;
                const float s2a = bf16f(sA[rr][cc]);
                const float s2b = bf16f(sB[cc][rr]);
                #pragma unroll
                for (int fm = 0; fm < 2; fm++)
                    #pragma unroll
                    for (int fh = 0; fh < 2; fh++) {
                        const float a = acc[fm][fh][cg][r];
                        rsum[fm][r]  += fast_exp2(fmaf(a, s2a, -CSHIFT));
                        csum[fh][cg] += fast_exp2(fmaf(a, s2b, -CSHIFT));
                    }
            }
        }

        // ---- reduce to mrg
        #pragma unroll
        for (int fm = 0; fm < 2; fm++) {
            #pragma unroll
            for (int r = 0; r < 4; r++) {
                float ss = rsum[fm][r];
                #pragma unroll
                for (int off = 1; off < 16; off <<= 1) ss += __shfl_xor(ss, off, 64);
                if (lc == 0) mrg[wn * 128 + fm * 64 + (wm * 16 + lk * 4 + r)] = ss;
            }
        }
        #pragma unroll
        for (int fh = 0; fh < 2; fh++) {
            #pragma unroll
            for (int cg = 0; cg < 2; cg++) {
                float ss = csum[fh][cg];
                ss += __shfl_xor(ss, 16, 64);
                ss += __shfl_xor(ss, 32, 64);
                if (l < 16) mrg[256 + wm * 128 + fh * 64 + (wn * 32 + cg * 16 + lc)] = ss;
            }
        }
        __syncthreads();   // barrier2: mrg ready; all LDS reads of this tile done

        if (tid < 128) {                 // row-view -> split j, rows of tile i
            int fm = tid >> 6, rho = tid & 63;
            float v = mrg[fm * 64 + rho] + mrg[128 + fm * 64 + rho];
            ssplit[(size_t)j * NN + (r64 + rho + fm * B_ROWS)] = v;
        } else if (!diag && tid < 256) { // col-view -> split i, rows of tile j
            int t2 = tid - 128, fh = t2 >> 6, cc = t2 & 63;
            float v = mrg[256 +   0 + fh * 64 + cc] + mrg[256 + 128 + fh * 64 + cc]
                    + mrg[256 + 256 + fh * 64 + cc] + mrg[256 + 384 + fh * 64 + cc];
            ssplit[(size_t)i * NN + (c64 + cc + fh * B_ROWS)] = v;
        }
        // next iteration's prologue writes ldsB/sA/sB only after barrier2;
        // mrg reads above complete before each wave re-enters barrier1.
    }
}

// ---- kernel 3a: parallel split-sum + lse (R21, proven) ----
__global__ __launch_bounds__(256)
void reduce_kernel(const float* __restrict__ ssplit, const float* __restrict__ pos2,
                   float* __restrict__ partial) {
    __shared__ float red[256];
    const int r = threadIdx.x & 31;
    const int s = threadIdx.x >> 5;
    const int n = blockIdx.x * 32 + r;              // n < 8192
    float ssum = 0.f;
    #pragma unroll
    for (int k = 0; k < 8; k++)
        ssum += ssplit[(size_t)(s + 8 * k) * NN + n];
    red[threadIdx.x] = ssum;
    __syncthreads();
    if (threadIdx.x < 32) {
        float t = 0.f;
        #pragma unroll
        for (int k = 0; k < 8; k++) t += red[threadIdx.x + 32 * k];
        float p = pos2[n & (B_ROWS - 1)];
        float Ssum = t + fast_exp2(p - CSHIFT);     // pos logit seeds the sum
        red[threadIdx.x] = (CSHIFT + log2f(Ssum)) - p;  // log2 units
    }
    __syncthreads();
    if (threadIdx.x == 0) {
        float acc = 0.f;
        #pragma unroll
        for (int k = 0; k < 32; k++) acc += red[k];
        partial[blockIdx.x] = acc;
    }
}

// ---- kernel 3b: deterministic final sum over 256 partials (LDS tree) ----
__global__ __launch_bounds__(256)
void final_kernel(const float* __restrict__ partial, float* __restrict__ out) {
    __shared__ float red[256];
    red[threadIdx.x] = partial[threadIdx.x];
    __syncthreads();
    for (int st = 128; st; st >>= 1) {
        if (threadIdx.x < st) red[threadIdx.x] += red[threadIdx.x + st];
        __syncthreads();
    }
    if (threadIdx.x == 0) out[0] = red[0] * (LN2 / (float)NN);
}

extern "C" void kernel_launch(void* const* d_in, const int* in_sizes, int n_in,
                              void* d_out, int out_size, void* d_ws, size_t ws_size,
                              hipStream_t stream) {
    (void)in_sizes; (void)n_in; (void)out_size; (void)ws_size;
    const float* hi = (const float*)d_in[0];
    const float* hj = (const float*)d_in[1];
    const float* S  = (const float*)d_in[2];

    char* ws = (char*)d_ws;
    __hip_bfloat16* hb = (__hip_bfloat16*)ws;                        // 2 MB
    float* pos2   = (float*)(ws + 2097152);                          // 16 KB
    float* ssplit = (float*)(ws + 2097152 + 16384);                  // 2 MB (64 splits)
    float* partial= (float*)(ws + 2097152 + 16384 + 2097152);        // 1 KB

    hpos_kernel<<<1024, 256, 0, stream>>>(hi, hj, hb, pos2);
    main_kernel<<<NBLK, 512, 0, stream>>>(hb, S, ssplit);
    reduce_kernel<<<256, 256, 0, stream>>>(ssplit, pos2, partial);
    final_kernel<<<1, 256, 0, stream>>>(partial, (float*)d_out);
}

// Round 27
// 46.740 us; speedup vs baseline: 1.1890x; 1.1890x over previous
//
#include <hip/hip_runtime.h>
#include <hip/hip_bf16.h>

// Problem constants
#define B_ROWS 4096
#define NN     8192
#define DD     128
#define NSPLIT 64           // split s of row n = the "other" tile index
#define NTRI   2080         // 64*65/2 upper-triangular tiles
#define SPA    68           // s2m panel row stride in u16 (136 B, 8B-aligned stores)
#define CSHIFT 128.0f       // fixed logsumexp shift (log2 domain)

typedef __attribute__((ext_vector_type(8))) short s8v;   // 8 bf16 (4 VGPR)
typedef __attribute__((ext_vector_type(4))) float f4v;   // 4 f32
typedef __attribute__((ext_vector_type(2))) float f2v;
typedef __attribute__((ext_vector_type(4))) unsigned short u16x4;
typedef unsigned int u32;

static constexpr float SCALE_H = 1.6986436f;      // sqrt(2*log2(e)); folds /TEMP and log2e into the matmul
static constexpr float SCALE2  = 2.8853900818f;   // 2*log2(e)
static constexpr float LN2     = 0.6931471805599453f;

__device__ __forceinline__ float fast_exp2(float x) {
#if __has_builtin(__builtin_amdgcn_exp2f)
    return __builtin_amdgcn_exp2f(x);      // bare v_exp_f32
#else
    return exp2f(x);
#endif
}

// (1 - x^2) with mask folded in, rounded to bf16 bits
__device__ __forceinline__ unsigned short s2m_pack(float x, bool msk) {
    float s2 = msk ? 0.f : 1.f - x * x;    // s2m=0 => exp2(-CSHIFT) -> ~0
    union { __hip_bfloat16 h; unsigned short u; } cv;
    cv.h = __float2bfloat16(s2);
    return cv.u;
}

__device__ __forceinline__ float bf16f(unsigned short u) {
    return __uint_as_float(((u32)u) << 16);
}

typedef __attribute__((address_space(1))) const u32 gu32;
typedef __attribute__((address_space(3))) u32 lu32;
__device__ __forceinline__ void gload_lds16(const void* g, void* l) {
    // async global->LDS, 16B/lane; dest = lds base + lane*16 (wave-uniform base)
    __builtin_amdgcn_global_load_lds((gu32*)g, (lu32*)l, 16, 0, 0);
}

// ---- kernel 1: fused bf16-prep + pos dot ----
__global__ void hpos_kernel(const float* __restrict__ hi, const float* __restrict__ hj,
                            __hip_bfloat16* __restrict__ hb, float* __restrict__ pos2) {
    int w = threadIdx.x >> 6, l = threadIdx.x & 63;
    int row = blockIdx.x * 4 + w;
    f2v a = ((const f2v*)(hi + (size_t)row * DD))[l];
    f2v b = ((const f2v*)(hj + (size_t)row * DD))[l];
    float d = a[0] * b[0] + a[1] * b[1];
    #pragma unroll
    for (int off = 32; off; off >>= 1) d += __shfl_xor(d, off, 64);
    if (l == 0) pos2[row] = SCALE2 * d;
    union { ushort2 u2; __hip_bfloat16 h[2]; } ua, ub;
    ua.h[0] = __float2bfloat16(a[0] * SCALE_H);
    ua.h[1] = __float2bfloat16(a[1] * SCALE_H);
    ub.h[0] = __float2bfloat16(b[0] * SCALE_H);
    ub.h[1] = __float2bfloat16(b[1] * SCALE_H);
    ((ushort2*)(hb + (size_t)row * DD))[l] = ua.u2;
    ((ushort2*)(hb + (size_t)(row + B_ROWS) * DD))[l] = ub.u2;
}

// ---- kernel 2: symmetric-tile fused sim*S2 + fixed-shift sum-of-exp2 ----
// R24 (best measured: 39.7 us main) + T5 s_setprio(1) around the compute
// phase. Blocks on a CU sit at different phases (prologue-load vs compute),
// so priority arbitration favors compute waves while loads fly -- the
// role-diversity regime where setprio measured +4-7% (attn, m191).
__global__ __launch_bounds__(512, 4)
void main_kernel(const __hip_bfloat16* __restrict__ hb, const float* __restrict__ S,
                 float* __restrict__ ssplit) {
    __shared__ short ldsB[128][128];           // 32 KB B tile (row-swizzled)
    __shared__ unsigned short sA[64][SPA];     // 8.5 KB row-view s2m (bf16)
    __shared__ unsigned short sB[64][SPA];     // 8.5 KB col-view s2m (bf16)
    __shared__ float mrg[768];                 // 3 KB merge scratch

    // XCD-bijective swizzle (2080 % 8 == 0) + triangular decode (i <= j)
    const int orig = blockIdx.x;
    const int bid  = (orig & 7) * (NTRI / 8) + (orig >> 3);
    int j = (int)((sqrtf(8.0f * (float)bid + 1.0f) - 1.0f) * 0.5f);
    while (((j + 1) * (j + 2)) / 2 <= bid) ++j;   // fixup fp error (exact)
    while ((j * (j + 1)) / 2 > bid) --j;
    const int i = bid - (j * (j + 1)) / 2;
    const bool diag = (i == j);

    const int tid = threadIdx.x;
    const int l  = tid & 63;
    const int w  = tid >> 6;                   // 0..7
    const int wm = w >> 1, wn = w & 1;
    const int lc = l & 15;                     // frag row/col within 16
    const int lk = l >> 4;                     // k-group
    const int r64 = i * 64, c64 = j * 64;

    const s8v* hb8 = (const s8v*)hb;           // 16 x s8v per row of 128 bf16

    const int prr = tid >> 3;                  // 0..63 (panel row)
    const int pc8 = (tid & 7) * 8;             // 0..56 (panel col base)

    // ---- (1) col-view S gather FIRST: longest memory chain (strided rows)
    f4v b0, b1;
    {
        const float* gB = S + (size_t)(c64 + prr) * B_ROWS + r64 + pc8;
        b0 = ((const f4v*)gB)[0]; b1 = ((const f4v*)gB)[1];
    }

    // ---- (2) async B tile stage: 128 hb-rows; 4 gloads/wave
    #pragma unroll
    for (int i2 = 0; i2 < 4; i2++) {
        const int rowb = w * 16 + i2 * 4;
        const int lrw  = rowb + lk;            // local row 0..127
        const int grow = c64 + ((lrw < 64) ? lrw : (lrw - 64 + B_ROWS));
        const int sc16 = lc ^ (lrw & 7);       // source pre-swizzle
        gload_lds16((const char*)hb + ((size_t)grow << 8) + (sc16 << 4),
                    (char*)&ldsB[rowb][0]);
    }

    // ---- (3) row-view S loads (coalesced)
    f4v a0, a1;
    {
        const float* gA = S + (size_t)(r64 + prr) * B_ROWS + c64 + pc8;
        a0 = ((const f4v*)gA)[0]; a1 = ((const f4v*)gA)[1];
    }

    // ---- (4) A fragments: wave's 16 pair-rows x 2 halves
    s8v afr[2][4];
    #pragma unroll
    for (int fm = 0; fm < 2; fm++) {
        int ar = (r64 + wm * 16 + lc) + fm * B_ROWS;
        #pragma unroll
        for (int kk = 0; kk < 4; kk++)
            afr[fm][kk] = hb8[ar * 16 + kk * 4 + lk];
    }

    // ---- (5) pack s2m panels (consumes a/b as they land)
    {
        u16x4 pa0, pa1, pb0, pb1;
        #pragma unroll
        for (int e = 0; e < 4; e++) {
            pa0[e] = s2m_pack(a0[e], diag && (pc8 + e     == prr));
            pa1[e] = s2m_pack(a1[e], diag && (pc8 + 4 + e == prr));
            pb0[e] = s2m_pack(b0[e], false);   // col-view discarded on diag
            pb1[e] = s2m_pack(b1[e], false);
        }
        *(u16x4*)&sA[prr][pc8]     = pa0;
        *(u16x4*)&sA[prr][pc8 + 4] = pa1;
        *(u16x4*)&sB[prr][pc8]     = pb0;
        *(u16x4*)&sB[prr][pc8 + 4] = pb1;
    }
    __syncthreads();   // B tile + panels + afr ready

    // ---- compute phase: prioritized (T5)
    __builtin_amdgcn_s_setprio(1);

    // MFMA: 32 per wave (fm2 x fh2 x cg2 x kk4), acc[fm][fh][cg]
    const char* bp[4];
    {
        const char* bb = (const char*)ldsB + (wn * 32 + lc) * 256;
        #pragma unroll
        for (int kk = 0; kk < 4; kk++)
            bp[kk] = bb + (((kk * 4 + lk) ^ (lc & 7)) << 4);
    }
    f4v acc[2][2][2];
    #pragma unroll
    for (int fm = 0; fm < 2; fm++)
        #pragma unroll
        for (int fh = 0; fh < 2; fh++)
            #pragma unroll
            for (int cg = 0; cg < 2; cg++) acc[fm][fh][cg] = f4v{0.f, 0.f, 0.f, 0.f};
    #pragma unroll
    for (int kk = 0; kk < 4; kk++) {
        #pragma unroll
        for (int fh = 0; fh < 2; fh++)
            #pragma unroll
            for (int cg = 0; cg < 2; cg++) {
                s8v bf = *(const s8v*)(bp[kk] + fh * 16384 + cg * 4096);
                acc[0][fh][cg] = __builtin_amdgcn_mfma_f32_16x16x32_bf16(
                    afr[0][kk], bf, acc[0][fh][cg], 0, 0, 0);
                acc[1][fh][cg] = __builtin_amdgcn_mfma_f32_16x16x32_bf16(
                    afr[1][kk], bf, acc[1][fh][cg], 0, 0, 0);
            }
    }

    // dual epilogue: row-view (sA[rr][cc]) + col-view (sB[cc][rr])
    float rsum[2][4], csum[2][2];
    #pragma unroll
    for (int fm = 0; fm < 2; fm++)
        #pragma unroll
        for (int r = 0; r < 4; r++) rsum[fm][r] = 0.f;
    csum[0][0] = csum[0][1] = csum[1][0] = csum[1][1] = 0.f;

    #pragma unroll
    for (int r = 0; r < 4; r++) {
        const int rr = wm * 16 + lk * 4 + r;
        #pragma unroll
        for (int cg = 0; cg < 2; cg++) {
            const int cc = wn * 32 + cg * 16 + lc;
            const float s2a = bf16f(sA[rr][cc]);
            const float s2b = bf16f(sB[cc][rr]);
            #pragma unroll
            for (int fm = 0; fm < 2; fm++)
                #pragma unroll
                for (int fh = 0; fh < 2; fh++) {
                    const float a = acc[fm][fh][cg][r];
                    rsum[fm][r]  += fast_exp2(fmaf(a, s2a, -CSHIFT));
                    csum[fh][cg] += fast_exp2(fmaf(a, s2b, -CSHIFT));
                }
        }
    }

    __builtin_amdgcn_s_setprio(0);

    // ---- row reduce (over lc) -> mrg[0..255]; col reduce (over lk) -> mrg[256..767]
    #pragma unroll
    for (int fm = 0; fm < 2; fm++) {
        #pragma unroll
        for (int r = 0; r < 4; r++) {
            float ss = rsum[fm][r];
            #pragma unroll
            for (int off = 1; off < 16; off <<= 1) ss += __shfl_xor(ss, off, 64);
            if (lc == 0) mrg[wn * 128 + fm * 64 + (wm * 16 + lk * 4 + r)] = ss;
        }
    }
    #pragma unroll
    for (int fh = 0; fh < 2; fh++) {
        #pragma unroll
        for (int cg = 0; cg < 2; cg++) {
            float ss = csum[fh][cg];
            ss += __shfl_xor(ss, 16, 64);
            ss += __shfl_xor(ss, 32, 64);
            if (l < 16) mrg[256 + wm * 128 + fh * 64 + (wn * 32 + cg * 16 + lc)] = ss;
        }
    }
    __syncthreads();

    if (tid < 128) {                 // row-view -> split j, rows of tile i
        int fm = tid >> 6, rho = tid & 63;
        float v = mrg[fm * 64 + rho] + mrg[128 + fm * 64 + rho];
        ssplit[(size_t)j * NN + (r64 + rho + fm * B_ROWS)] = v;
    } else if (!diag && tid < 256) { // col-view -> split i, rows of tile j
        int t2 = tid - 128, fh = t2 >> 6, cc = t2 & 63;
        float v = mrg[256 +   0 + fh * 64 + cc] + mrg[256 + 128 + fh * 64 + cc]
                + mrg[256 + 256 + fh * 64 + cc] + mrg[256 + 384 + fh * 64 + cc];
        ssplit[(size_t)i * NN + (c64 + cc + fh * B_ROWS)] = v;
    }
}

// ---- kernel 3a: parallel split-sum + lse (R21, proven) ----
__global__ __launch_bounds__(256)
void reduce_kernel(const float* __restrict__ ssplit, const float* __restrict__ pos2,
                   float* __restrict__ partial) {
    __shared__ float red[256];
    const int r = threadIdx.x & 31;
    const int s = threadIdx.x >> 5;
    const int n = blockIdx.x * 32 + r;              // n < 8192
    float ssum = 0.f;
    #pragma unroll
    for (int k = 0; k < 8; k++)
        ssum += ssplit[(size_t)(s + 8 * k) * NN + n];
    red[threadIdx.x] = ssum;
    __syncthreads();
    if (threadIdx.x < 32) {
        float t = 0.f;
        #pragma unroll
        for (int k = 0; k < 8; k++) t += red[threadIdx.x + 32 * k];
        float p = pos2[n & (B_ROWS - 1)];
        float Ssum = t + fast_exp2(p - CSHIFT);     // pos logit seeds the sum
        red[threadIdx.x] = (CSHIFT + log2f(Ssum)) - p;  // log2 units
    }
    __syncthreads();
    if (threadIdx.x == 0) {
        float acc = 0.f;
        #pragma unroll
        for (int k = 0; k < 32; k++) acc += red[k];
        partial[blockIdx.x] = acc;
    }
}

// ---- kernel 3b: deterministic final sum over 256 partials (LDS tree) ----
__global__ __launch_bounds__(256)
void final_kernel(const float* __restrict__ partial, float* __restrict__ out) {
    __shared__ float red[256];
    red[threadIdx.x] = partial[threadIdx.x];
    __syncthreads();
    for (int st = 128; st; st >>= 1) {
        if (threadIdx.x < st) red[threadIdx.x] += red[threadIdx.x + st];
        __syncthreads();
    }
    if (threadIdx.x == 0) out[0] = red[0] * (LN2 / (float)NN);
}

extern "C" void kernel_launch(void* const* d_in, const int* in_sizes, int n_in,
                              void* d_out, int out_size, void* d_ws, size_t ws_size,
                              hipStream_t stream) {
    (void)in_sizes; (void)n_in; (void)out_size; (void)ws_size;
    const float* hi = (const float*)d_in[0];
    const float* hj = (const float*)d_in[1];
    const float* S  = (const float*)d_in[2];

    char* ws = (char*)d_ws;
    __hip_bfloat16* hb = (__hip_bfloat16*)ws;                        // 2 MB
    float* pos2   = (float*)(ws + 2097152);                          // 16 KB
    float* ssplit = (float*)(ws + 2097152 + 16384);                  // 2 MB (64 splits)
    float* partial= (float*)(ws + 2097152 + 16384 + 2097152);        // 1 KB

    hpos_kernel<<<1024, 256, 0, stream>>>(hi, hj, hb, pos2);
    main_kernel<<<NTRI, 512, 0, stream>>>(hb, S, ssplit);
    reduce_kernel<<<256, 256, 0, stream>>>(ssplit, pos2, partial);
    final_kernel<<<1, 256, 0, stream>>>(partial, (float*)d_out);
}

// Round 28
// 42.898 us; speedup vs baseline: 1.2954x; 1.0896x over previous
//
#include <hip/hip_runtime.h>
#include <hip/hip_bf16.h>

// Problem constants
#define B_ROWS 4096
#define NN     8192
#define DD     128
#define NSPLIT 64           // split s of row n = the "other" tile index
#define NTRI   2080         // 64*65/2 upper-triangular tiles
#define SPA    68           // s2m panel row stride in u16 (136 B, 8B-aligned stores)
#define CSHIFT 128.0f       // fixed logsumexp shift (log2 domain)

typedef __attribute__((ext_vector_type(8))) short s8v;   // 8 bf16 (4 VGPR)
typedef __attribute__((ext_vector_type(4))) float f4v;   // 4 f32
typedef __attribute__((ext_vector_type(2))) float f2v;
typedef __attribute__((ext_vector_type(4))) unsigned short u16x4;
typedef unsigned int u32;

static constexpr float SCALE_H = 1.6986436f;      // sqrt(2*log2(e)); folds /TEMP and log2e into the matmul
static constexpr float SCALE2  = 2.8853900818f;   // 2*log2(e)
static constexpr float LN2     = 0.6931471805599453f;

__device__ __forceinline__ float fast_exp2(float x) {
#if __has_builtin(__builtin_amdgcn_exp2f)
    return __builtin_amdgcn_exp2f(x);      // bare v_exp_f32
#else
    return exp2f(x);
#endif
}

// (1 - x^2) with mask folded in, rounded to bf16 bits
__device__ __forceinline__ unsigned short s2m_pack(float x, bool msk) {
    float s2 = msk ? 0.f : 1.f - x * x;    // s2m=0 => exp2(-CSHIFT) -> ~0
    union { __hip_bfloat16 h; unsigned short u; } cv;
    cv.h = __float2bfloat16(s2);
    return cv.u;
}

__device__ __forceinline__ float bf16f(unsigned short u) {
    return __uint_as_float(((u32)u) << 16);
}

typedef __attribute__((address_space(1))) const u32 gu32;
typedef __attribute__((address_space(3))) u32 lu32;
__device__ __forceinline__ void gload_lds16(const void* g, void* l) {
    // async global->LDS, 16B/lane; dest = lds base + lane*16 (wave-uniform base)
    __builtin_amdgcn_global_load_lds((gu32*)g, (lu32*)l, 16, 0, 0);
}

// ---- kernel 1: fused bf16-prep + pos dot ----
__global__ void hpos_kernel(const float* __restrict__ hi, const float* __restrict__ hj,
                            __hip_bfloat16* __restrict__ hb, float* __restrict__ pos2) {
    int w = threadIdx.x >> 6, l = threadIdx.x & 63;
    int row = blockIdx.x * 4 + w;
    f2v a = ((const f2v*)(hi + (size_t)row * DD))[l];
    f2v b = ((const f2v*)(hj + (size_t)row * DD))[l];
    float d = a[0] * b[0] + a[1] * b[1];
    #pragma unroll
    for (int off = 32; off; off >>= 1) d += __shfl_xor(d, off, 64);
    if (l == 0) pos2[row] = SCALE2 * d;
    union { ushort2 u2; __hip_bfloat16 h[2]; } ua, ub;
    ua.h[0] = __float2bfloat16(a[0] * SCALE_H);
    ua.h[1] = __float2bfloat16(a[1] * SCALE_H);
    ub.h[0] = __float2bfloat16(b[0] * SCALE_H);
    ub.h[1] = __float2bfloat16(b[1] * SCALE_H);
    ((ushort2*)(hb + (size_t)row * DD))[l] = ua.u2;
    ((ushort2*)(hb + (size_t)(row + B_ROWS) * DD))[l] = ub.u2;
}

// ---- kernel 2: symmetric-tile fused sim*S2 + fixed-shift sum-of-exp2 ----
// R24 FINAL (best measured: 43.0 us total). Longest-latency-first prologue:
// col-view S gather (16KB lane stride, worst chain) issued FIRST, then async
// B stage, then coalesced row-view S, then A frags, then pack; one barrier
// drains all. Dual epilogue exploits sim symmetry (each tile computed once).
__global__ __launch_bounds__(512, 4)
void main_kernel(const __hip_bfloat16* __restrict__ hb, const float* __restrict__ S,
                 float* __restrict__ ssplit) {
    __shared__ short ldsB[128][128];           // 32 KB B tile (row-swizzled)
    __shared__ unsigned short sA[64][SPA];     // 8.5 KB row-view s2m (bf16)
    __shared__ unsigned short sB[64][SPA];     // 8.5 KB col-view s2m (bf16)
    __shared__ float mrg[768];                 // 3 KB merge scratch

    // XCD-bijective swizzle (2080 % 8 == 0) + triangular decode (i <= j)
    const int orig = blockIdx.x;
    const int bid  = (orig & 7) * (NTRI / 8) + (orig >> 3);
    int j = (int)((sqrtf(8.0f * (float)bid + 1.0f) - 1.0f) * 0.5f);
    while (((j + 1) * (j + 2)) / 2 <= bid) ++j;   // fixup fp error (exact)
    while ((j * (j + 1)) / 2 > bid) --j;
    const int i = bid - (j * (j + 1)) / 2;
    const bool diag = (i == j);

    const int tid = threadIdx.x;
    const int l  = tid & 63;
    const int w  = tid >> 6;                   // 0..7
    const int wm = w >> 1, wn = w & 1;
    const int lc = l & 15;                     // frag row/col within 16
    const int lk = l >> 4;                     // k-group
    const int r64 = i * 64, c64 = j * 64;

    const s8v* hb8 = (const s8v*)hb;           // 16 x s8v per row of 128 bf16

    const int prr = tid >> 3;                  // 0..63 (panel row)
    const int pc8 = (tid & 7) * 8;             // 0..56 (panel col base)

    // ---- (1) col-view S gather FIRST: longest memory chain (strided rows)
    f4v b0, b1;
    {
        const float* gB = S + (size_t)(c64 + prr) * B_ROWS + r64 + pc8;
        b0 = ((const f4v*)gB)[0]; b1 = ((const f4v*)gB)[1];
    }

    // ---- (2) async B tile stage: 128 hb-rows; 4 gloads/wave
    #pragma unroll
    for (int i2 = 0; i2 < 4; i2++) {
        const int rowb = w * 16 + i2 * 4;
        const int lrw  = rowb + lk;            // local row 0..127
        const int grow = c64 + ((lrw < 64) ? lrw : (lrw - 64 + B_ROWS));
        const int sc16 = lc ^ (lrw & 7);       // source pre-swizzle
        gload_lds16((const char*)hb + ((size_t)grow << 8) + (sc16 << 4),
                    (char*)&ldsB[rowb][0]);
    }

    // ---- (3) row-view S loads (coalesced)
    f4v a0, a1;
    {
        const float* gA = S + (size_t)(r64 + prr) * B_ROWS + c64 + pc8;
        a0 = ((const f4v*)gA)[0]; a1 = ((const f4v*)gA)[1];
    }

    // ---- (4) A fragments: wave's 16 pair-rows x 2 halves
    s8v afr[2][4];
    #pragma unroll
    for (int fm = 0; fm < 2; fm++) {
        int ar = (r64 + wm * 16 + lc) + fm * B_ROWS;
        #pragma unroll
        for (int kk = 0; kk < 4; kk++)
            afr[fm][kk] = hb8[ar * 16 + kk * 4 + lk];
    }

    // ---- (5) pack s2m panels (consumes a/b as they land)
    {
        u16x4 pa0, pa1, pb0, pb1;
        #pragma unroll
        for (int e = 0; e < 4; e++) {
            pa0[e] = s2m_pack(a0[e], diag && (pc8 + e     == prr));
            pa1[e] = s2m_pack(a1[e], diag && (pc8 + 4 + e == prr));
            pb0[e] = s2m_pack(b0[e], false);   // col-view discarded on diag
            pb1[e] = s2m_pack(b1[e], false);
        }
        *(u16x4*)&sA[prr][pc8]     = pa0;
        *(u16x4*)&sA[prr][pc8 + 4] = pa1;
        *(u16x4*)&sB[prr][pc8]     = pb0;
        *(u16x4*)&sB[prr][pc8 + 4] = pb1;
    }
    __syncthreads();   // B tile + panels + afr ready

    // ---- MFMA: 32 per wave (fm2 x fh2 x cg2 x kk4), acc[fm][fh][cg]
    const char* bp[4];
    {
        const char* bb = (const char*)ldsB + (wn * 32 + lc) * 256;
        #pragma unroll
        for (int kk = 0; kk < 4; kk++)
            bp[kk] = bb + (((kk * 4 + lk) ^ (lc & 7)) << 4);
    }
    f4v acc[2][2][2];
    #pragma unroll
    for (int fm = 0; fm < 2; fm++)
        #pragma unroll
        for (int fh = 0; fh < 2; fh++)
            #pragma unroll
            for (int cg = 0; cg < 2; cg++) acc[fm][fh][cg] = f4v{0.f, 0.f, 0.f, 0.f};
    #pragma unroll
    for (int kk = 0; kk < 4; kk++) {
        #pragma unroll
        for (int fh = 0; fh < 2; fh++)
            #pragma unroll
            for (int cg = 0; cg < 2; cg++) {
                s8v bf = *(const s8v*)(bp[kk] + fh * 16384 + cg * 4096);
                acc[0][fh][cg] = __builtin_amdgcn_mfma_f32_16x16x32_bf16(
                    afr[0][kk], bf, acc[0][fh][cg], 0, 0, 0);
                acc[1][fh][cg] = __builtin_amdgcn_mfma_f32_16x16x32_bf16(
                    afr[1][kk], bf, acc[1][fh][cg], 0, 0, 0);
            }
    }

    // ---- dual epilogue: row-view (sA[rr][cc]) + col-view (sB[cc][rr])
    float rsum[2][4], csum[2][2];
    #pragma unroll
    for (int fm = 0; fm < 2; fm++)
        #pragma unroll
        for (int r = 0; r < 4; r++) rsum[fm][r] = 0.f;
    csum[0][0] = csum[0][1] = csum[1][0] = csum[1][1] = 0.f;

    #pragma unroll
    for (int r = 0; r < 4; r++) {
        const int rr = wm * 16 + lk * 4 + r;
        #pragma unroll
        for (int cg = 0; cg < 2; cg++) {
            const int cc = wn * 32 + cg * 16 + lc;
            const float s2a = bf16f(sA[rr][cc]);
            const float s2b = bf16f(sB[cc][rr]);
            #pragma unroll
            for (int fm = 0; fm < 2; fm++)
                #pragma unroll
                for (int fh = 0; fh < 2; fh++) {
                    const float a = acc[fm][fh][cg][r];
                    rsum[fm][r]  += fast_exp2(fmaf(a, s2a, -CSHIFT));
                    csum[fh][cg] += fast_exp2(fmaf(a, s2b, -CSHIFT));
                }
        }
    }

    // ---- row reduce (over lc) -> mrg[0..255]; col reduce (over lk) -> mrg[256..767]
    #pragma unroll
    for (int fm = 0; fm < 2; fm++) {
        #pragma unroll
        for (int r = 0; r < 4; r++) {
            float ss = rsum[fm][r];
            #pragma unroll
            for (int off = 1; off < 16; off <<= 1) ss += __shfl_xor(ss, off, 64);
            if (lc == 0) mrg[wn * 128 + fm * 64 + (wm * 16 + lk * 4 + r)] = ss;
        }
    }
    #pragma unroll
    for (int fh = 0; fh < 2; fh++) {
        #pragma unroll
        for (int cg = 0; cg < 2; cg++) {
            float ss = csum[fh][cg];
            ss += __shfl_xor(ss, 16, 64);
            ss += __shfl_xor(ss, 32, 64);
            if (l < 16) mrg[256 + wm * 128 + fh * 64 + (wn * 32 + cg * 16 + lc)] = ss;
        }
    }
    __syncthreads();

    if (tid < 128) {                 // row-view -> split j, rows of tile i
        int fm = tid >> 6, rho = tid & 63;
        float v = mrg[fm * 64 + rho] + mrg[128 + fm * 64 + rho];
        ssplit[(size_t)j * NN + (r64 + rho + fm * B_ROWS)] = v;
    } else if (!diag && tid < 256) { // col-view -> split i, rows of tile j
        int t2 = tid - 128, fh = t2 >> 6, cc = t2 & 63;
        float v = mrg[256 +   0 + fh * 64 + cc] + mrg[256 + 128 + fh * 64 + cc]
                + mrg[256 + 256 + fh * 64 + cc] + mrg[256 + 384 + fh * 64 + cc];
        ssplit[(size_t)i * NN + (c64 + cc + fh * B_ROWS)] = v;
    }
}

// ---- kernel 3a: parallel split-sum + lse (R21, proven) ----
__global__ __launch_bounds__(256)
void reduce_kernel(const float* __restrict__ ssplit, const float* __restrict__ pos2,
                   float* __restrict__ partial) {
    __shared__ float red[256];
    const int r = threadIdx.x & 31;
    const int s = threadIdx.x >> 5;
    const int n = blockIdx.x * 32 + r;              // n < 8192
    float ssum = 0.f;
    #pragma unroll
    for (int k = 0; k < 8; k++)
        ssum += ssplit[(size_t)(s + 8 * k) * NN + n];
    red[threadIdx.x] = ssum;
    __syncthreads();
    if (threadIdx.x < 32) {
        float t = 0.f;
        #pragma unroll
        for (int k = 0; k < 8; k++) t += red[threadIdx.x + 32 * k];
        float p = pos2[n & (B_ROWS - 1)];
        float Ssum = t + fast_exp2(p - CSHIFT);     // pos logit seeds the sum
        red[threadIdx.x] = (CSHIFT + log2f(Ssum)) - p;  // log2 units
    }
    __syncthreads();
    if (threadIdx.x == 0) {
        float acc = 0.f;
        #pragma unroll
        for (int k = 0; k < 32; k++) acc += red[k];
        partial[blockIdx.x] = acc;
    }
}

// ---- kernel 3b: deterministic final sum over 256 partials (LDS tree) ----
__global__ __launch_bounds__(256)
void final_kernel(const float* __restrict__ partial, float* __restrict__ out) {
    __shared__ float red[256];
    red[threadIdx.x] = partial[threadIdx.x];
    __syncthreads();
    for (int st = 128; st; st >>= 1) {
        if (threadIdx.x < st) red[threadIdx.x] += red[threadIdx.x + st];
        __syncthreads();
    }
    if (threadIdx.x == 0) out[0] = red[0] * (LN2 / (float)NN);
}

extern "C" void kernel_launch(void* const* d_in, const int* in_sizes, int n_in,
                              void* d_out, int out_size, void* d_ws, size_t ws_size,
                              hipStream_t stream) {
    (void)in_sizes; (void)n_in; (void)out_size; (void)ws_size;
    const float* hi = (const float*)d_in[0];
    const float* hj = (const float*)d_in[1];
    const float* S  = (const float*)d_in[2];

    char* ws = (char*)d_ws;
    __hip_bfloat16* hb = (__hip_bfloat16*)ws;                        // 2 MB
    float* pos2   = (float*)(ws + 2097152);                          // 16 KB
    float* ssplit = (float*)(ws + 2097152 + 16384);                  // 2 MB (64 splits)
    float* partial= (float*)(ws + 2097152 + 16384 + 2097152);        // 1 KB

    hpos_kernel<<<1024, 256, 0, stream>>>(hi, hj, hb, pos2);
    main_kernel<<<NTRI, 512, 0, stream>>>(hb, S, ssplit);
    reduce_kernel<<<256, 256, 0, stream>>>(ssplit, pos2, partial);
    final_kernel<<<1, 256, 0, stream>>>(partial, (float*)d_out);
}

// Round 29
// 42.411 us; speedup vs baseline: 1.3103x; 1.0115x over previous
//
#include <hip/hip_runtime.h>
#include <hip/hip_bf16.h>

// Problem constants
#define B_ROWS 4096
#define NN     8192
#define DD     128
#define NSPLIT 64           // split s of row n = the "other" tile index
#define NTRI   2080         // 64*65/2 upper-triangular tiles
#define SPA    68           // s2m panel row stride in u16 (136 B, 8B-aligned stores)
#define CSHIFT 128.0f       // fixed logsumexp shift (log2 domain)

typedef __attribute__((ext_vector_type(8))) short s8v;   // 8 bf16 (4 VGPR)
typedef __attribute__((ext_vector_type(4))) float f4v;   // 4 f32
typedef __attribute__((ext_vector_type(2))) float f2v;
typedef __attribute__((ext_vector_type(4))) unsigned short u16x4;
typedef unsigned int u32;

static constexpr float SCALE_H = 1.6986436f;      // sqrt(2*log2(e)); folds /TEMP and log2e into the matmul
static constexpr float SCALE2  = 2.8853900818f;   // 2*log2(e)
static constexpr float LN2     = 0.6931471805599453f;

__device__ __forceinline__ float fast_exp2(float x) {
#if __has_builtin(__builtin_amdgcn_exp2f)
    return __builtin_amdgcn_exp2f(x);      // bare v_exp_f32
#else
    return exp2f(x);
#endif
}

// (1 - x^2) with mask folded in, rounded to bf16 bits
__device__ __forceinline__ unsigned short s2m_pack(float x, bool msk) {
    float s2 = msk ? 0.f : 1.f - x * x;    // s2m=0 => exp2(-CSHIFT) -> ~0
    union { __hip_bfloat16 h; unsigned short u; } cv;
    cv.h = __float2bfloat16(s2);
    return cv.u;
}

__device__ __forceinline__ float bf16f(unsigned short u) {
    return __uint_as_float(((u32)u) << 16);
}

typedef __attribute__((address_space(1))) const u32 gu32;
typedef __attribute__((address_space(3))) u32 lu32;
__device__ __forceinline__ void gload_lds16(const void* g, void* l) {
    // async global->LDS, 16B/lane; dest = lds base + lane*16 (wave-uniform base)
    __builtin_amdgcn_global_load_lds((gu32*)g, (lu32*)l, 16, 0, 0);
}

// ---- kernel 1: fused bf16-prep + pos dot ----
__global__ void hpos_kernel(const float* __restrict__ hi, const float* __restrict__ hj,
                            __hip_bfloat16* __restrict__ hb, float* __restrict__ pos2) {
    int w = threadIdx.x >> 6, l = threadIdx.x & 63;
    int row = blockIdx.x * 4 + w;
    f2v a = ((const f2v*)(hi + (size_t)row * DD))[l];
    f2v b = ((const f2v*)(hj + (size_t)row * DD))[l];
    float d = a[0] * b[0] + a[1] * b[1];
    #pragma unroll
    for (int off = 32; off; off >>= 1) d += __shfl_xor(d, off, 64);
    if (l == 0) pos2[row] = SCALE2 * d;
    union { ushort2 u2; __hip_bfloat16 h[2]; } ua, ub;
    ua.h[0] = __float2bfloat16(a[0] * SCALE_H);
    ua.h[1] = __float2bfloat16(a[1] * SCALE_H);
    ub.h[0] = __float2bfloat16(b[0] * SCALE_H);
    ub.h[1] = __float2bfloat16(b[1] * SCALE_H);
    ((ushort2*)(hb + (size_t)row * DD))[l] = ua.u2;
    ((ushort2*)(hb + (size_t)(row + B_ROWS) * DD))[l] = ub.u2;
}

// ---- kernel 2: symmetric-tile fused sim*S2 + fixed-shift sum-of-exp2 ----
// FINAL (best measured: 42.9 us total). Longest-latency-first prologue:
// col-view S gather issued FIRST, then async B stage, then coalesced
// row-view S, then A frags, then pack; one barrier drains all. Dual
// epilogue exploits sim symmetry (each 64x64 pair-tile computed once).
__global__ __launch_bounds__(512, 4)
void main_kernel(const __hip_bfloat16* __restrict__ hb, const float* __restrict__ S,
                 float* __restrict__ ssplit) {
    __shared__ short ldsB[128][128];           // 32 KB B tile (row-swizzled)
    __shared__ unsigned short sA[64][SPA];     // 8.5 KB row-view s2m (bf16)
    __shared__ unsigned short sB[64][SPA];     // 8.5 KB col-view s2m (bf16)
    __shared__ float mrg[768];                 // 3 KB merge scratch

    // XCD-bijective swizzle (2080 % 8 == 0) + triangular decode (i <= j)
    const int orig = blockIdx.x;
    const int bid  = (orig & 7) * (NTRI / 8) + (orig >> 3);
    int j = (int)((sqrtf(8.0f * (float)bid + 1.0f) - 1.0f) * 0.5f);
    while (((j + 1) * (j + 2)) / 2 <= bid) ++j;   // fixup fp error (exact)
    while ((j * (j + 1)) / 2 > bid) --j;
    const int i = bid - (j * (j + 1)) / 2;
    const bool diag = (i == j);

    const int tid = threadIdx.x;
    const int l  = tid & 63;
    const int w  = tid >> 6;                   // 0..7
    const int wm = w >> 1, wn = w & 1;
    const int lc = l & 15;                     // frag row/col within 16
    const int lk = l >> 4;                     // k-group
    const int r64 = i * 64, c64 = j * 64;

    const s8v* hb8 = (const s8v*)hb;           // 16 x s8v per row of 128 bf16

    const int prr = tid >> 3;                  // 0..63 (panel row)
    const int pc8 = (tid & 7) * 8;             // 0..56 (panel col base)

    // ---- (1) col-view S gather FIRST: longest memory chain
    f4v b0, b1;
    {
        const float* gB = S + (size_t)(c64 + prr) * B_ROWS + r64 + pc8;
        b0 = ((const f4v*)gB)[0]; b1 = ((const f4v*)gB)[1];
    }

    // ---- (2) async B tile stage: 128 hb-rows; 4 gloads/wave
    #pragma unroll
    for (int i2 = 0; i2 < 4; i2++) {
        const int rowb = w * 16 + i2 * 4;
        const int lrw  = rowb + lk;            // local row 0..127
        const int grow = c64 + ((lrw < 64) ? lrw : (lrw - 64 + B_ROWS));
        const int sc16 = lc ^ (lrw & 7);       // source pre-swizzle
        gload_lds16((const char*)hb + ((size_t)grow << 8) + (sc16 << 4),
                    (char*)&ldsB[rowb][0]);
    }

    // ---- (3) row-view S loads (coalesced)
    f4v a0, a1;
    {
        const float* gA = S + (size_t)(r64 + prr) * B_ROWS + c64 + pc8;
        a0 = ((const f4v*)gA)[0]; a1 = ((const f4v*)gA)[1];
    }

    // ---- (4) A fragments: wave's 16 pair-rows x 2 halves
    s8v afr[2][4];
    #pragma unroll
    for (int fm = 0; fm < 2; fm++) {
        int ar = (r64 + wm * 16 + lc) + fm * B_ROWS;
        #pragma unroll
        for (int kk = 0; kk < 4; kk++)
            afr[fm][kk] = hb8[ar * 16 + kk * 4 + lk];
    }

    // ---- (5) pack s2m panels (consumes a/b as they land)
    {
        u16x4 pa0, pa1, pb0, pb1;
        #pragma unroll
        for (int e = 0; e < 4; e++) {
            pa0[e] = s2m_pack(a0[e], diag && (pc8 + e     == prr));
            pa1[e] = s2m_pack(a1[e], diag && (pc8 + 4 + e == prr));
            pb0[e] = s2m_pack(b0[e], false);   // col-view discarded on diag
            pb1[e] = s2m_pack(b1[e], false);
        }
        *(u16x4*)&sA[prr][pc8]     = pa0;
        *(u16x4*)&sA[prr][pc8 + 4] = pa1;
        *(u16x4*)&sB[prr][pc8]     = pb0;
        *(u16x4*)&sB[prr][pc8 + 4] = pb1;
    }
    __syncthreads();   // B tile + panels + afr ready

    // ---- MFMA: 32 per wave (fm2 x fh2 x cg2 x kk4), acc[fm][fh][cg]
    const char* bp[4];
    {
        const char* bb = (const char*)ldsB + (wn * 32 + lc) * 256;
        #pragma unroll
        for (int kk = 0; kk < 4; kk++)
            bp[kk] = bb + (((kk * 4 + lk) ^ (lc & 7)) << 4);
    }
    f4v acc[2][2][2];
    #pragma unroll
    for (int fm = 0; fm < 2; fm++)
        #pragma unroll
        for (int fh = 0; fh < 2; fh++)
            #pragma unroll
            for (int cg = 0; cg < 2; cg++) acc[fm][fh][cg] = f4v{0.f, 0.f, 0.f, 0.f};
    #pragma unroll
    for (int kk = 0; kk < 4; kk++) {
        #pragma unroll
        for (int fh = 0; fh < 2; fh++)
            #pragma unroll
            for (int cg = 0; cg < 2; cg++) {
                s8v bf = *(const s8v*)(bp[kk] + fh * 16384 + cg * 4096);
                acc[0][fh][cg] = __builtin_amdgcn_mfma_f32_16x16x32_bf16(
                    afr[0][kk], bf, acc[0][fh][cg], 0, 0, 0);
                acc[1][fh][cg] = __builtin_amdgcn_mfma_f32_16x16x32_bf16(
                    afr[1][kk], bf, acc[1][fh][cg], 0, 0, 0);
            }
    }

    // ---- dual epilogue: row-view (sA[rr][cc]) + col-view (sB[cc][rr])
    float rsum[2][4], csum[2][2];
    #pragma unroll
    for (int fm = 0; fm < 2; fm++)
        #pragma unroll
        for (int r = 0; r < 4; r++) rsum[fm][r] = 0.f;
    csum[0][0] = csum[0][1] = csum[1][0] = csum[1][1] = 0.f;

    #pragma unroll
    for (int r = 0; r < 4; r++) {
        const int rr = wm * 16 + lk * 4 + r;
        #pragma unroll
        for (int cg = 0; cg < 2; cg++) {
            const int cc = wn * 32 + cg * 16 + lc;
            const float s2a = bf16f(sA[rr][cc]);
            const float s2b = bf16f(sB[cc][rr]);
            #pragma unroll
            for (int fm = 0; fm < 2; fm++)
                #pragma unroll
                for (int fh = 0; fh < 2; fh++) {
                    const float a = acc[fm][fh][cg][r];
                    rsum[fm][r]  += fast_exp2(fmaf(a, s2a, -CSHIFT));
                    csum[fh][cg] += fast_exp2(fmaf(a, s2b, -CSHIFT));
                }
        }
    }

    // ---- row reduce (over lc) -> mrg[0..255]; col reduce (over lk) -> mrg[256..767]
    #pragma unroll
    for (int fm = 0; fm < 2; fm++) {
        #pragma unroll
        for (int r = 0; r < 4; r++) {
            float ss = rsum[fm][r];
            #pragma unroll
            for (int off = 1; off < 16; off <<= 1) ss += __shfl_xor(ss, off, 64);
            if (lc == 0) mrg[wn * 128 + fm * 64 + (wm * 16 + lk * 4 + r)] = ss;
        }
    }
    #pragma unroll
    for (int fh = 0; fh < 2; fh++) {
        #pragma unroll
        for (int cg = 0; cg < 2; cg++) {
            float ss = csum[fh][cg];
            ss += __shfl_xor(ss, 16, 64);
            ss += __shfl_xor(ss, 32, 64);
            if (l < 16) mrg[256 + wm * 128 + fh * 64 + (wn * 32 + cg * 16 + lc)] = ss;
        }
    }
    __syncthreads();

    if (tid < 128) {                 // row-view -> split j, rows of tile i
        int fm = tid >> 6, rho = tid & 63;
        float v = mrg[fm * 64 + rho] + mrg[128 + fm * 64 + rho];
        ssplit[(size_t)j * NN + (r64 + rho + fm * B_ROWS)] = v;
    } else if (!diag && tid < 256) { // col-view -> split i, rows of tile j
        int t2 = tid - 128, fh = t2 >> 6, cc = t2 & 63;
        float v = mrg[256 +   0 + fh * 64 + cc] + mrg[256 + 128 + fh * 64 + cc]
                + mrg[256 + 256 + fh * 64 + cc] + mrg[256 + 384 + fh * 64 + cc];
        ssplit[(size_t)i * NN + (c64 + cc + fh * B_ROWS)] = v;
    }
}

// ---- kernel 3a: parallel split-sum + lse ----
__global__ __launch_bounds__(256)
void reduce_kernel(const float* __restrict__ ssplit, const float* __restrict__ pos2,
                   float* __restrict__ partial) {
    __shared__ float red[256];
    const int r = threadIdx.x & 31;
    const int s = threadIdx.x >> 5;
    const int n = blockIdx.x * 32 + r;              // n < 8192
    float ssum = 0.f;
    #pragma unroll
    for (int k = 0; k < 8; k++)
        ssum += ssplit[(size_t)(s + 8 * k) * NN + n];
    red[threadIdx.x] = ssum;
    __syncthreads();
    if (threadIdx.x < 32) {
        float t = 0.f;
        #pragma unroll
        for (int k = 0; k < 8; k++) t += red[threadIdx.x + 32 * k];
        float p = pos2[n & (B_ROWS - 1)];
        float Ssum = t + fast_exp2(p - CSHIFT);     // pos logit seeds the sum
        red[threadIdx.x] = (CSHIFT + log2f(Ssum)) - p;  // log2 units
    }
    __syncthreads();
    if (threadIdx.x == 0) {
        float acc = 0.f;
        #pragma unroll
        for (int k = 0; k < 32; k++) acc += red[k];
        partial[blockIdx.x] = acc;
    }
}

// ---- kernel 3b: deterministic final sum over 256 partials (LDS tree) ----
__global__ __launch_bounds__(256)
void final_kernel(const float* __restrict__ partial, float* __restrict__ out) {
    __shared__ float red[256];
    red[threadIdx.x] = partial[threadIdx.x];
    __syncthreads();
    for (int st = 128; st; st >>= 1) {
        if (threadIdx.x < st) red[threadIdx.x] += red[threadIdx.x + st];
        __syncthreads();
    }
    if (threadIdx.x == 0) out[0] = red[0] * (LN2 / (float)NN);
}

extern "C" void kernel_launch(void* const* d_in, const int* in_sizes, int n_in,
                              void* d_out, int out_size, void* d_ws, size_t ws_size,
                              hipStream_t stream) {
    (void)in_sizes; (void)n_in; (void)out_size; (void)ws_size;
    const float* hi = (const float*)d_in[0];
    const float* hj = (const float*)d_in[1];
    const float* S  = (const float*)d_in[2];

    char* ws = (char*)d_ws;
    __hip_bfloat16* hb = (__hip_bfloat16*)ws;                        // 2 MB
    float* pos2   = (float*)(ws + 2097152);                          // 16 KB
    float* ssplit = (float*)(ws + 2097152 + 16384);                  // 2 MB (64 splits)
    float* partial= (float*)(ws + 2097152 + 16384 + 2097152);        // 1 KB

    hpos_kernel<<<1024, 256, 0, stream>>>(hi, hj, hb, pos2);
    main_kernel<<<NTRI, 512, 0, stream>>>(hb, S, ssplit);
    reduce_kernel<<<256, 256, 0, stream>>>(ssplit, pos2, partial);
    final_kernel<<<1, 256, 0, stream>>>(partial, (float*)d_out);
}